// Round 7
// baseline (645.354 us; speedup 1.0000x reference)
//
#include <hip/hip_runtime.h>

typedef __attribute__((ext_vector_type(8))) short short8;
typedef __attribute__((ext_vector_type(4))) float f32x4;
typedef unsigned short u16;
typedef unsigned int u32;
typedef unsigned long long u64;

// params layout (floats)
#define P_WH 0   // softmax(p_hidden)[2]
#define P_WI 2   // softmax(p_inter)[2]
#define P_WA 4   // softmax(p_abit)[2]
#define P_WW 6   // softmax(p_wbit)[2]
#define SL_AX 8      // absmax x: quadrants (r0=1024,c0=1024)
#define SL_WUP 12    // quadrants
#define SL_WGATE 16
#define SL_WDOWN 20
#define SL_AH 24     // absmax h: cols<2752, >=2752 (partial)
#define P_SX 28      // s_x[i][bit] (4)
#define P_SWUP 32    // s[i][j][l]  (8)
#define P_SWGATE 40
#define P_SWDOWN 48
#define P_SH 56      // s_h[i][bit] (4)

__device__ __forceinline__ u16 f2bf(float f) {
  u32 u = __float_as_uint(f);
  u = (u + 0x7FFFu + ((u >> 16) & 1u)) >> 16;
  return (u16)u;
}
__device__ __forceinline__ float bf2f(u16 h) { return __uint_as_float(((u32)h) << 16); }
__device__ __forceinline__ float fquant(float v, float s) { return rintf(v / s) * s; }

typedef const __attribute__((address_space(1))) u32 gl_u32;
typedef __attribute__((address_space(3))) u32 lds_u32;
__device__ __forceinline__ void gload_lds16(const void* g, void* l) {
  __builtin_amdgcn_global_load_lds((gl_u32*)g, (lds_u32*)l, 16, 0, 0);
}

#define WAITVM8()  asm volatile("s_waitcnt vmcnt(8)" ::: "memory")
#define WAITVM0()  asm volatile("s_waitcnt vmcnt(0)" ::: "memory")
#define BARRIER()  asm volatile("s_barrier" ::: "memory")

// ---- init: zero absmax slots, compute the four 2-way softmaxes ----
__global__ void k_init(const float* ph, const float* pi, const float* pa,
                       const float* pw, float* P) {
  if (threadIdx.x == 0) {
    u32* U = (u32*)P;
    for (int i = SL_AX; i < SL_AH + 2; ++i) U[i] = 0u;
    const float* src[4] = {ph, pi, pa, pw};
    #pragma unroll
    for (int t = 0; t < 4; ++t) {
      float a = src[t][0], b = src[t][1];
      float mx = fmaxf(a, b);
      float ea = expf(a - mx), eb = expf(b - mx);
      float s = ea + eb;
      P[t * 2 + 0] = ea / s;
      P[t * 2 + 1] = eb / s;
    }
  }
}

// ---- quadrant absmax: branchless, ILP-4, magic-div, block-reduced ----
__device__ __forceinline__ void amax_proc(float4 d, int v, u32 magic, int C,
                                          int r0, int c0,
                                          float& m0, float& m1, float& m2, float& m3) {
  int lin = v << 2;
  int o = (int)(((u64)(u32)lin * magic) >> 40);
  int c = lin - o * C;
  float mm = fmaxf(fmaxf(fabsf(d.x), fabsf(d.y)), fmaxf(fabsf(d.z), fabsf(d.w)));
  bool rlo = o < r0, clo = c < c0;
  m0 = fmaxf(m0, (rlo && clo) ? mm : 0.f);
  m1 = fmaxf(m1, (rlo && !clo) ? mm : 0.f);
  m2 = fmaxf(m2, (!rlo && clo) ? mm : 0.f);
  m3 = fmaxf(m3, (!rlo && !clo) ? mm : 0.f);
}

__device__ __forceinline__ void absmax_dev(const float4* __restrict__ A4,
                                           int nvec, u32 magic, int C, int r0, int c0,
                                           int slotbase, float* P, int bid, int nb) {
  float m0 = 0.f, m1 = 0.f, m2 = 0.f, m3 = 0.f;
  const int tid = threadIdx.x;
  const int step = nb * 256;
  int v = bid * 256 + tid;
  for (; v + 3 * step < nvec; v += 4 * step) {
    float4 d0 = A4[v];
    float4 d1 = A4[v + step];
    float4 d2 = A4[v + 2 * step];
    float4 d3 = A4[v + 3 * step];
    amax_proc(d0, v,            magic, C, r0, c0, m0, m1, m2, m3);
    amax_proc(d1, v + step,     magic, C, r0, c0, m0, m1, m2, m3);
    amax_proc(d2, v + 2 * step, magic, C, r0, c0, m0, m1, m2, m3);
    amax_proc(d3, v + 3 * step, magic, C, r0, c0, m0, m1, m2, m3);
  }
  for (; v < nvec; v += step) {
    float4 d0 = A4[v];
    amax_proc(d0, v, magic, C, r0, c0, m0, m1, m2, m3);
  }
  #pragma unroll
  for (int off = 32; off > 0; off >>= 1) {
    m0 = fmaxf(m0, __shfl_xor(m0, off));
    m1 = fmaxf(m1, __shfl_xor(m1, off));
    m2 = fmaxf(m2, __shfl_xor(m2, off));
    m3 = fmaxf(m3, __shfl_xor(m3, off));
  }
  __shared__ float red[16];
  const int wave = tid >> 6;
  if ((tid & 63) == 0) {
    red[wave * 4 + 0] = m0;
    red[wave * 4 + 1] = m1;
    red[wave * 4 + 2] = m2;
    red[wave * 4 + 3] = m3;
  }
  __syncthreads();
  if (tid < 4) {
    float mm = fmaxf(fmaxf(red[tid], red[4 + tid]), fmaxf(red[8 + tid], red[12 + tid]));
    if (mm > 0.f) atomicMax((u32*)P + slotbase + tid, __float_as_uint(mm));
  }
}

// ---- fused absmax over all 4 tensors (one launch) ----
__global__ __launch_bounds__(256) void k_absmax4(const float* x, const float* Wu,
                                                 const float* Wg, const float* Wd,
                                                 u32 magic2048, u32 magic5504, float* P) {
  int b = blockIdx.x;
  if (b < 256)        absmax_dev((const float4*)x,  (1024 * 2048) >> 2, magic2048, 2048, 1024, 1024, SL_AX,    P, b,        256);
  else if (b < 768)   absmax_dev((const float4*)Wu, (5504 * 2048) >> 2, magic2048, 2048, 2752, 1024, SL_WUP,   P, b - 256,  512);
  else if (b < 1280)  absmax_dev((const float4*)Wg, (5504 * 2048) >> 2, magic2048, 2048, 2752, 1024, SL_WGATE, P, b - 768,  512);
  else                absmax_dev((const float4*)Wd, (2048 * 5504) >> 2, magic5504, 5504, 1024, 2752, SL_WDOWN, P, b - 1280, 512);
}

// ---- scales: s = max(absmax/qmax, 1e-8), qmax in {7,127} ----
__global__ void k_params1(float* P) {
  if (threadIdx.x != 0 || blockIdx.x != 0) return;
  u32* U = (u32*)P;
  float x00 = __uint_as_float(U[SL_AX + 0]);
  float x01 = __uint_as_float(U[SL_AX + 1]);
  float ax0 = x00;
  float ax1 = fmaxf(x00, x01);
  P[P_SX + 0] = fmaxf(ax0 / 7.f, 1e-8f);
  P[P_SX + 1] = fmaxf(ax0 / 127.f, 1e-8f);
  P[P_SX + 2] = fmaxf(ax1 / 7.f, 1e-8f);
  P[P_SX + 3] = fmaxf(ax1 / 127.f, 1e-8f);
  const int sl[3] = {SL_WUP, SL_WGATE, SL_WDOWN};
  const int sb[3] = {P_SWUP, P_SWGATE, P_SWDOWN};
  #pragma unroll
  for (int t = 0; t < 3; ++t) {
    float q00 = __uint_as_float(U[sl[t] + 0]);
    float q01 = __uint_as_float(U[sl[t] + 1]);
    float q10 = __uint_as_float(U[sl[t] + 2]);
    float q11 = __uint_as_float(U[sl[t] + 3]);
    float a0 = q00;
    float a1 = fmaxf(q00, q10);
    float a2 = fmaxf(q00, q01);
    float a3 = fmaxf(fmaxf(q00, q01), fmaxf(q10, q11));
    float aa[4] = {a0, a1, a2, a3};
    #pragma unroll
    for (int ij = 0; ij < 4; ++ij) {
      P[sb[t] + ij * 2 + 0] = fmaxf(aa[ij] / 7.f, 1e-8f);
      P[sb[t] + ij * 2 + 1] = fmaxf(aa[ij] / 127.f, 1e-8f);
    }
  }
}

__global__ void k_params2(float* P) {
  if (threadIdx.x != 0 || blockIdx.x != 0) return;
  u32* U = (u32*)P;
  float a0 = __uint_as_float(U[SL_AH]);
  float a1 = fmaxf(a0, __uint_as_float(U[SL_AH + 1]));
  P[P_SH + 0] = fmaxf(a0 / 7.f, 1e-8f);
  P[P_SH + 1] = fmaxf(a0 / 127.f, 1e-8f);
  P[P_SH + 2] = fmaxf(a1 / 7.f, 1e-8f);
  P[P_SH + 3] = fmaxf(a1 / 127.f, 1e-8f);
}

// ---- build combined activation operand, K-concat over in_sizes, hi/lo bf16,
//      stored chunk-XOR pre-swizzled: out chunk (kc>>3)&3 ^ ((row>>1)&3) ----
__global__ __launch_bounds__(256) void k_build_x(
    const float* __restrict__ src, const float* __restrict__ P,
    u16* __restrict__ Xh, u16* __restrict__ Xl,
    int rows, int Csrc, int cin0, int K, int sbx) {
  int kpr = K >> 3;
  int nch = rows * kpr;
  int gid = blockIdx.x * blockDim.x + threadIdx.x;
  if (gid >= nch) return;
  int row = gid / kpr;
  int kc_out = (gid - row * kpr) << 3;
  int kc_log = kc_out ^ (((row >> 1) & 3) << 3);
  int i = (kc_log >= cin0) ? 1 : 0;
  int c = kc_log - i * cin0;
  float pin = P[P_WH + i];
  float wa0 = P[P_WA], wa1 = P[P_WA + 1];
  float s4 = P[sbx + i * 2], s8 = P[sbx + i * 2 + 1];
  const float* sp = src + (size_t)row * Csrc + c;
  float v[8];
  *(float4*)&v[0] = *(const float4*)sp;
  *(float4*)&v[4] = *(const float4*)(sp + 4);
  short8 hv, lv;
  #pragma unroll
  for (int e = 0; e < 8; ++e) {
    float val = pin * (wa0 * fquant(v[e], s4) + wa1 * fquant(v[e], s8));
    u16 h = f2bf(val);
    hv[e] = (short)h;
    lv[e] = (short)f2bf(val - bf2f(h));
  }
  size_t off = (size_t)row * K + kc_out;
  *(short8*)(Xh + off) = hv;
  *(short8*)(Xl + off) = lv;
}

// ---- build combined weight operand (sum over out_sizes j and w_bits l) ----
__global__ __launch_bounds__(256) void k_build_w(
    const float* __restrict__ W, const float* __restrict__ P,
    u16* __restrict__ Wh, u16* __restrict__ Wl,
    int R, int Csrc, int cin0, int K, int sbw, int cout0) {
  int kpr = K >> 3;
  int nch = R * kpr;
  int gid = blockIdx.x * blockDim.x + threadIdx.x;
  if (gid >= nch) return;
  int row = gid / kpr;
  int kc_out = (gid - row * kpr) << 3;
  int kc_log = kc_out ^ (((row >> 1) & 3) << 3);
  int i = (kc_log >= cin0) ? 1 : 0;
  int c = kc_log - i * cin0;
  float wi0 = P[P_WI], wi1 = P[P_WI + 1];
  float ww0 = P[P_WW], ww1 = P[P_WW + 1];
  float s00 = P[sbw + i * 4 + 0];
  float s01 = P[sbw + i * 4 + 1];
  float s10 = P[sbw + i * 4 + 2];
  float s11 = P[sbw + i * 4 + 3];
  float keep0 = (row < cout0) ? wi0 : 0.f;
  const float* sp = W + (size_t)row * Csrc + c;
  float v[8];
  *(float4*)&v[0] = *(const float4*)sp;
  *(float4*)&v[4] = *(const float4*)(sp + 4);
  short8 hv, lv;
  #pragma unroll
  for (int e = 0; e < 8; ++e) {
    float w = v[e];
    float t0 = ww0 * fquant(w, s00) + ww1 * fquant(w, s01);
    float t1 = ww0 * fquant(w, s10) + ww1 * fquant(w, s11);
    float val = keep0 * t0 + wi1 * t1;
    u16 h = f2bf(val);
    hv[e] = (short)h;
    lv[e] = (short)f2bf(val - bf2f(h));
  }
  size_t off = (size_t)row * K + kc_out;
  *(short8*)(Wh + off) = hv;
  *(short8*)(Wl + off) = lv;
}

// ---- h = silu(gate)*up, fused h-absmax (cols<2752 / >=2752).
//      U_/G_ point at up/gate values, both with row stride `stride`. ----
__global__ __launch_bounds__(256) void k_h(const float* __restrict__ U_,
                                           const float* __restrict__ G_,
                                           int stride, float* __restrict__ H_,
                                           float* P) {
  int nvec = (1024 * 5504) >> 2;
  int gstride = gridDim.x * blockDim.x;
  float m0 = 0.f, m1 = 0.f;
  for (int v = blockIdx.x * blockDim.x + threadIdx.x; v < nvec; v += gstride) {
    int lin = v << 2;
    int r = lin / 5504;            // compile-time constant divisor -> magic mul
    int c = lin - r * 5504;
    size_t o = (size_t)r * stride + c;
    float4 u = *(const float4*)(U_ + o);
    float4 g = *(const float4*)(G_ + o);
    float4 h;
    h.x = u.x * (g.x / (1.f + expf(-g.x)));
    h.y = u.y * (g.y / (1.f + expf(-g.y)));
    h.z = u.z * (g.z / (1.f + expf(-g.z)));
    h.w = u.w * (g.w / (1.f + expf(-g.w)));
    ((float4*)H_)[v] = h;
    float mm = fmaxf(fmaxf(fabsf(h.x), fabsf(h.y)), fmaxf(fabsf(h.z), fabsf(h.w)));
    if (c < 2752) m0 = fmaxf(m0, mm); else m1 = fmaxf(m1, mm);
  }
  #pragma unroll
  for (int off = 32; off > 0; off >>= 1) {
    m0 = fmaxf(m0, __shfl_xor(m0, off));
    m1 = fmaxf(m1, __shfl_xor(m1, off));
  }
  if ((threadIdx.x & 63) == 0) {
    u32* slots = (u32*)P;
    if (m0 > 0.f) atomicMax(slots + SL_AH, __float_as_uint(m0));
    if (m1 > 0.f) atomicMax(slots + SL_AH + 1, __float_as_uint(m1));
  }
}

// ---- bf16x3 MFMA GEMM, 128x128 tile, depth-2 counted-vmcnt pipeline (64KB LDS,
//      2 blocks/CU), XCD-swizzled, optional split-K via gridDim.z. ----
template <int MF, int NF>
__global__ __launch_bounds__(256) void k_gemm(
    const u16* __restrict__ Ah, const u16* __restrict__ Al,
    const u16* __restrict__ Bh, const u16* __restrict__ Bl,
    float* __restrict__ C, int M, int N, int K) {
  constexpr int BM = MF * 32;
  constexpr int BN = NF * 32;
  constexpr int HALF = (2 * BM + 2 * BN) * 32;  // u16 elements per buffer
  constexpr int nsegA = BM / 16;
  constexpr int nsegB = BN / 16;
  constexpr int NSEG = 2 * nsegA + 2 * nsegB;
  constexpr int NJ = NSEG / 4;
  static_assert(NJ == 8, "vmcnt immediates assume 8 loads per stage");
  __shared__ __align__(16) u16 S[2 * HALF];

  const int tid = threadIdx.x;
  const int wave = tid >> 6;
  const int lane = tid & 63;

  // XCD-bijective block swizzle (per z-slice)
  const int gx = gridDim.x;
  const int nwg = gx * gridDim.y;
  const int orig = blockIdx.y * gx + blockIdx.x;
  const int q = nwg >> 3, r = nwg & 7;
  const int xcd = orig & 7, linb = orig >> 3;
  const int swz = (xcd < r ? xcd * (q + 1) : r * (q + 1) + (xcd - r) * q) + linb;
  const int m0 = (swz % gx) * BM;
  const int n0 = (swz / gx) * BN;

  // split-K ranges from gridDim.z
  const int St = K >> 5;             // total K-steps of 32
  const int Z = gridDim.z;
  const int zb = St / Z, zr = St - zb * Z;
  const int z = blockIdx.z;
  const int nst = zb + ((z < zr) ? 1 : 0);
  const int k0 = (z * zb + ((z < zr) ? z : zr)) << 5;

  const int wr = wave >> 1, wc = wave & 1;
  const int lrow = lane >> 2;         // staging: row within 16-row segment
  const int lcol = (lane & 3) << 3;   // staging: col chunk
  const int fr = lane & 15;
  const int fq4 = (lane >> 4) << 2;
  const int kofs = (lane >> 4) << 3;

  f32x4 acc[MF][NF];
  #pragma unroll
  for (int m = 0; m < MF; ++m)
    #pragma unroll
    for (int n = 0; n < NF; ++n) acc[m][n] = (f32x4){0.f, 0.f, 0.f, 0.f};

  // staging sources (at k0) / LDS offsets
  const u16* srcp[NJ];
  int loff[NJ];
  #pragma unroll
  for (int j = 0; j < NJ; ++j) {
    int g = j * 4 + wave;
    const u16* gb; int abase, trow, segi;
    if (g < nsegA)               { gb = Ah; abase = 0;                  trow = m0; segi = g; }
    else if (g < 2 * nsegA)      { gb = Al; abase = BM * 32;            trow = m0; segi = g - nsegA; }
    else if (g < 2 * nsegA + nsegB) { gb = Bh; abase = 2 * BM * 32;     trow = n0; segi = g - 2 * nsegA; }
    else                         { gb = Bl; abase = 2 * BM * 32 + BN * 32; trow = n0; segi = g - 2 * nsegA - nsegB; }
    srcp[j] = gb + (size_t)(trow + segi * 16 + lrow) * K + (k0 + lcol);
    loff[j] = abase + segi * 512;
  }

  // fragment LDS offsets (loop-invariant)
  int aoh[MF], aol[MF], boh[NF], bol[NF];
  #pragma unroll
  for (int m = 0; m < MF; ++m) {
    int rr = wr * (MF * 16) + m * 16 + fr;
    int idx = rr * 32 + (kofs ^ (((rr >> 1) & 3) << 3));
    aoh[m] = idx;
    aol[m] = BM * 32 + idx;
  }
  #pragma unroll
  for (int n = 0; n < NF; ++n) {
    int rr = wc * (NF * 16) + n * 16 + fr;
    int idx = rr * 32 + (kofs ^ (((rr >> 1) & 3) << 3));
    boh[n] = 2 * BM * 32 + idx;
    bol[n] = 2 * BM * 32 + BN * 32 + idx;
  }

  #define STAGE(bufo)                                           \
    { _Pragma("unroll")                                         \
      for (int j = 0; j < NJ; ++j) {                            \
        gload_lds16(srcp[j], S + (bufo) + loff[j]);             \
        srcp[j] += 32;                                          \
      } }

  #define COMPUTE(bufo)                                                         \
    { short8 afh[MF], afl[MF], bfh[NF], bfl[NF];                                \
      _Pragma("unroll")                                                         \
      for (int m = 0; m < MF; ++m) {                                            \
        afh[m] = *(const short8*)(S + (bufo) + aoh[m]);                         \
        afl[m] = *(const short8*)(S + (bufo) + aol[m]);                         \
      }                                                                         \
      _Pragma("unroll")                                                         \
      for (int n = 0; n < NF; ++n) {                                            \
        bfh[n] = *(const short8*)(S + (bufo) + boh[n]);                         \
        bfl[n] = *(const short8*)(S + (bufo) + bol[n]);                         \
      }                                                                         \
      _Pragma("unroll")                                                         \
      for (int m = 0; m < MF; ++m)                                              \
        _Pragma("unroll")                                                       \
        for (int n = 0; n < NF; ++n) {                                          \
          acc[m][n] = __builtin_amdgcn_mfma_f32_16x16x32_bf16(afh[m], bfh[n], acc[m][n], 0, 0, 0); \
          acc[m][n] = __builtin_amdgcn_mfma_f32_16x16x32_bf16(afh[m], bfl[n], acc[m][n], 0, 0, 0); \
          acc[m][n] = __builtin_amdgcn_mfma_f32_16x16x32_bf16(afl[m], bfh[n], acc[m][n], 0, 0, 0); \
        } }

  // depth-2 counted-vmcnt pipeline: stage(t+1) issued BEFORE compute(t);
  // its 8 loads stay in flight across both barriers (vmcnt(8), never 0 in-loop).
  int curo = 0;
  STAGE(curo);
  for (int t = 0; t + 1 < nst; ++t) {
    STAGE(curo ^ HALF);          // 16 outstanding per wave
    WAITVM8();                   // tile t landed (per wave, in-order)
    BARRIER();                   // -> landed for all waves
    COMPUTE(curo);
    BARRIER();                   // all waves done reading curo before next STAGE into it
    curo ^= HALF;
  }
  WAITVM0();                     // last tile's 8
  BARRIER();
  COMPUTE(curo);

  #undef STAGE
  #undef COMPUTE

  float* Cz = C + (size_t)z * M * N;
  #pragma unroll
  for (int m = 0; m < MF; ++m) {
    #pragma unroll
    for (int n = 0; n < NF; ++n) {
      int row = m0 + wr * (MF * 16) + m * 16 + fq4;
      int col = n0 + wc * (NF * 16) + n * 16 + fr;
      float* cp = Cz + (size_t)row * N + col;
      f32x4 a = acc[m][n];
      cp[0] = a[0];
      cp[(size_t)N] = a[1];
      cp[(size_t)2 * N] = a[2];
      cp[(size_t)3 * N] = a[3];
    }
  }
}

// ---- out = p0 + p1 + p2 + p3 (split-K z=4 reduce, deterministic order) ----
__global__ __launch_bounds__(256) void k_reduce4(const float4* __restrict__ p,
                                                 float4* __restrict__ out, int nvec) {
  int stride = gridDim.x * blockDim.x;
  for (int i = blockIdx.x * blockDim.x + threadIdx.x; i < nvec; i += stride) {
    float4 a = p[i], b = p[nvec + i], c = p[2 * nvec + i], d = p[3 * nvec + i];
    float4 o;
    o.x = ((a.x + b.x) + c.x) + d.x;
    o.y = ((a.y + b.y) + c.y) + d.y;
    o.z = ((a.z + b.z) + c.z) + d.z;
    o.w = ((a.w + b.w) + c.w) + d.w;
    out[i] = o;
  }
}

extern "C" void kernel_launch(void* const* d_in, const int* in_sizes, int n_in,
                              void* d_out, int out_size, void* d_ws, size_t ws_size,
                              hipStream_t stream) {
  const float* x  = (const float*)d_in[0];
  const float* ph = (const float*)d_in[1];
  const float* pi = (const float*)d_in[2];
  const float* pa = (const float*)d_in[3];
  const float* pw = (const float*)d_in[4];
  const float* Wg = (const float*)d_in[5];
  const float* Wu = (const float*)d_in[6];
  const float* Wd = (const float*)d_in[7];
  float* out = (float*)d_out;

  const u32 magic2048 = (u32)(((1ULL << 40) + 2047ULL) / 2048ULL);
  const u32 magic5504 = (u32)(((1ULL << 40) + 5503ULL) / 5504ULL);
  char* ws = (char*)d_ws;

  // ---- fused layout (needs ~215.5 MB) ----
  const size_t szX1 = (size_t)1024 * 3072 * 2;          // 6.29 MB each
  const size_t szWug = (size_t)11008 * 3072 * 2;        // 67.63 MB each (h, l)
  const size_t szC = (size_t)1024 * 11008 * 4;          // 45.09 MB
  const size_t szH = (size_t)1024 * 5504 * 4;           // 22.54 MB
  const size_t fused_need = 1024 + 2 * szX1 + 2 * szWug + szC + szH;

  if (ws_size >= fused_need) {
    // ---------------- fused up+gate path ----------------
    size_t off = 0;
    float* P = (float*)(ws + off); off += 1024;
    u16* X1h = (u16*)(ws + off); off += szX1;
    u16* X1l = (u16*)(ws + off); off += szX1;
    u16* Wh  = (u16*)(ws + off); off += szWug;   // rows 0..5503 Wu, 5504..11007 Wg
    u16* Wl  = (u16*)(ws + off); off += szWug;
    float* C = (float*)(ws + off); off += szC;   // [1024][11008] = [UP | GATE]
    float* H = (float*)(ws + off); off += szH;
    // reuse: X2 inside C (33.8 <= 45.1); down weights inside Wh/Wl heads;
    // DPART in Wh tail (disjoint from down-Wh head)
    u16* X2h = (u16*)C;
    u16* X2l = (u16*)C + (size_t)1024 * 8256;
    const size_t szWd = (size_t)2048 * 8256 * 2;   // 33.82 MB
    u16* Wdh = Wh;
    u16* Wdl = Wl;
    float* DPART = (float*)((char*)Wh + szWd);     // 33.55 MB fits in remaining 33.82

    k_init<<<1, 64, 0, stream>>>(ph, pi, pa, pw, P);
    k_absmax4<<<1792, 256, 0, stream>>>(x, Wu, Wg, Wd, magic2048, magic5504, P);
    k_params1<<<1, 64, 0, stream>>>(P);

    {
      int nch = 1024 * (3072 / 8);
      k_build_x<<<(nch + 255) / 256, 256, 0, stream>>>(x, P, X1h, X1l, 1024, 2048, 1024, 3072, P_SX);
    }
    {
      int nch = 5504 * (3072 / 8);
      k_build_w<<<(nch + 255) / 256, 256, 0, stream>>>(Wu, P, Wh, Wl, 5504, 2048, 1024, 3072, P_SWUP, 2752);
      k_build_w<<<(nch + 255) / 256, 256, 0, stream>>>(Wg, P, Wh + (size_t)5504 * 3072,
                                                       Wl + (size_t)5504 * 3072, 5504, 2048, 1024, 3072, P_SWGATE, 2752);
    }
    dim3 g1(1024 / 128, 11008 / 128, 1);   // 688 blocks, one dispatch
    k_gemm<4, 4><<<g1, 256, 0, stream>>>(X1h, X1l, Wh, Wl, C, 1024, 11008, 3072);

    k_h<<<2048, 256, 0, stream>>>(C, C + 5504, 11008, H, P);
    k_params2<<<1, 64, 0, stream>>>(P);

    {
      int nch = 1024 * (8256 / 8);
      k_build_x<<<(nch + 255) / 256, 256, 0, stream>>>(H, P, X2h, X2l, 1024, 5504, 2752, 8256, P_SH);
    }
    {
      int nch = 2048 * (8256 / 8);
      k_build_w<<<(nch + 255) / 256, 256, 0, stream>>>(Wd, P, Wdh, Wdl, 2048, 5504, 2752, 8256, P_SWDOWN, 1024);
    }
    dim3 g2(1024 / 128, 2048 / 128, 4);    // 512 blocks = 2/CU perfect fill
    k_gemm<4, 4><<<g2, 256, 0, stream>>>(X2h, X2l, Wdh, Wdl, DPART, 1024, 2048, 8256);
    k_reduce4<<<2048, 256, 0, stream>>>((const float4*)DPART, (float4*)out, (1024 * 2048) / 4);
    return;
  }

  // ---------------- fallback: round-6 layout (needs ~159 MB) ----------------
  size_t off = 0;
  float* P = (float*)(ws + off); off += 1024;
  u16* X1h = (u16*)(ws + off); off += szX1;
  u16* X1l = (u16*)(ws + off); off += szX1;
  u16* Wh  = (u16*)(ws + off); off += (size_t)5504 * 3072 * 2;
  u16* Wl  = (u16*)(ws + off); off += (size_t)5504 * 3072 * 2;
  float* UP   = (float*)(ws + off); off += (size_t)1024 * 5504 * 4;
  float* GATE = (float*)(ws + off); off += (size_t)1024 * 5504 * 4;
  u16* X2h = (u16*)(ws + off); off += (size_t)1024 * 8256 * 2;
  u16* X2l = (u16*)(ws + off); off += (size_t)1024 * 8256 * 2;
  float* H = UP;
  float* DPART = UP;
  if (ws_size < off) return;

  k_init<<<1, 64, 0, stream>>>(ph, pi, pa, pw, P);
  k_absmax4<<<1792, 256, 0, stream>>>(x, Wu, Wg, Wd, magic2048, magic5504, P);
  k_params1<<<1, 64, 0, stream>>>(P);

  {
    int nch = 1024 * (3072 / 8);
    k_build_x<<<(nch + 255) / 256, 256, 0, stream>>>(x, P, X1h, X1l, 1024, 2048, 1024, 3072, P_SX);
  }
  {
    int nch = 5504 * (3072 / 8);
    k_build_w<<<(nch + 255) / 256, 256, 0, stream>>>(Wu, P, Wh, Wl, 5504, 2048, 1024, 3072, P_SWUP, 2752);
  }
  dim3 g1(1024 / 128, 5504 / 128, 1);
  k_gemm<4, 4><<<g1, 256, 0, stream>>>(X1h, X1l, Wh, Wl, UP, 1024, 5504, 3072);
  {
    int nch = 5504 * (3072 / 8);
    k_build_w<<<(nch + 255) / 256, 256, 0, stream>>>(Wg, P, Wh, Wl, 5504, 2048, 1024, 3072, P_SWGATE, 2752);
  }
  k_gemm<4, 4><<<g1, 256, 0, stream>>>(X1h, X1l, Wh, Wl, GATE, 1024, 5504, 3072);

  k_h<<<2048, 256, 0, stream>>>(UP, GATE, 5504, H, P);
  k_params2<<<1, 64, 0, stream>>>(P);

  {
    int nch = 1024 * (8256 / 8);
    k_build_x<<<(nch + 255) / 256, 256, 0, stream>>>(H, P, X2h, X2l, 1024, 5504, 2752, 8256, P_SH);
  }
  {
    int nch = 2048 * (8256 / 8);
    k_build_w<<<(nch + 255) / 256, 256, 0, stream>>>(Wd, P, Wh, Wl, 2048, 5504, 2752, 8256, P_SWDOWN, 1024);
  }
  dim3 g2(1024 / 128, 2048 / 128, 4);
  k_gemm<4, 4><<<g2, 256, 0, stream>>>(X2h, X2l, Wh, Wl, DPART, 1024, 2048, 8256);
  k_reduce4<<<2048, 256, 0, stream>>>((const float4*)DPART, (float4*)out, (1024 * 2048) / 4);
}

// Round 8
// 633.443 us; speedup vs baseline: 1.0188x; 1.0188x over previous
//
#include <hip/hip_runtime.h>

typedef __attribute__((ext_vector_type(8))) short short8;
typedef __attribute__((ext_vector_type(4))) float f32x4;
typedef unsigned short u16;
typedef unsigned int u32;
typedef unsigned long long u64;

// params layout (floats)
#define P_WH 0   // softmax(p_hidden)[2]
#define P_WI 2   // softmax(p_inter)[2]
#define P_WA 4   // softmax(p_abit)[2]
#define P_WW 6   // softmax(p_wbit)[2]
#define SL_AX 8      // absmax x: quadrants (r0=1024,c0=1024)
#define SL_WUP 12    // quadrants
#define SL_WGATE 16
#define SL_WDOWN 20
#define SL_AH 24     // absmax h: cols<2752, >=2752 (partial)
#define P_SX 28      // s_x[i][bit] (4)
#define P_SWUP 32    // s[i][j][l]  (8)
#define P_SWGATE 40
#define P_SWDOWN 48
#define P_SH 56      // s_h[i][bit] (4)

__device__ __forceinline__ u16 f2bf(float f) {
  u32 u = __float_as_uint(f);
  u = (u + 0x7FFFu + ((u >> 16) & 1u)) >> 16;
  return (u16)u;
}
__device__ __forceinline__ float bf2f(u16 h) { return __uint_as_float(((u32)h) << 16); }
__device__ __forceinline__ float fquant(float v, float s) { return rintf(v / s) * s; }

typedef const __attribute__((address_space(1))) u32 gl_u32;
typedef __attribute__((address_space(3))) u32 lds_u32;
__device__ __forceinline__ void gload_lds16(const void* g, void* l) {
  __builtin_amdgcn_global_load_lds((gl_u32*)g, (lds_u32*)l, 16, 0, 0);
}

#define WAITVM8()  asm volatile("s_waitcnt vmcnt(8)" ::: "memory")
#define WAITVM6()  asm volatile("s_waitcnt vmcnt(6)" ::: "memory")
#define WAITVM0()  asm volatile("s_waitcnt vmcnt(0)" ::: "memory")
#define BARRIER()  asm volatile("s_barrier" ::: "memory")

// ---- init: zero absmax slots, compute the four 2-way softmaxes ----
__global__ void k_init(const float* ph, const float* pi, const float* pa,
                       const float* pw, float* P) {
  if (threadIdx.x == 0) {
    u32* U = (u32*)P;
    for (int i = SL_AX; i < SL_AH + 2; ++i) U[i] = 0u;
    const float* src[4] = {ph, pi, pa, pw};
    #pragma unroll
    for (int t = 0; t < 4; ++t) {
      float a = src[t][0], b = src[t][1];
      float mx = fmaxf(a, b);
      float ea = expf(a - mx), eb = expf(b - mx);
      float s = ea + eb;
      P[t * 2 + 0] = ea / s;
      P[t * 2 + 1] = eb / s;
    }
  }
}

// ---- quadrant absmax: branchless, ILP-4, magic-div, block-reduced ----
__device__ __forceinline__ void amax_proc(float4 d, int v, u32 magic, int C,
                                          int r0, int c0,
                                          float& m0, float& m1, float& m2, float& m3) {
  int lin = v << 2;
  int o = (int)(((u64)(u32)lin * magic) >> 40);
  int c = lin - o * C;
  float mm = fmaxf(fmaxf(fabsf(d.x), fabsf(d.y)), fmaxf(fabsf(d.z), fabsf(d.w)));
  bool rlo = o < r0, clo = c < c0;
  m0 = fmaxf(m0, (rlo && clo) ? mm : 0.f);
  m1 = fmaxf(m1, (rlo && !clo) ? mm : 0.f);
  m2 = fmaxf(m2, (!rlo && clo) ? mm : 0.f);
  m3 = fmaxf(m3, (!rlo && !clo) ? mm : 0.f);
}

__device__ __forceinline__ void absmax_dev(const float4* __restrict__ A4,
                                           int nvec, u32 magic, int C, int r0, int c0,
                                           int slotbase, float* P, int bid, int nb) {
  float m0 = 0.f, m1 = 0.f, m2 = 0.f, m3 = 0.f;
  const int tid = threadIdx.x;
  const int step = nb * 256;
  int v = bid * 256 + tid;
  for (; v + 3 * step < nvec; v += 4 * step) {
    float4 d0 = A4[v];
    float4 d1 = A4[v + step];
    float4 d2 = A4[v + 2 * step];
    float4 d3 = A4[v + 3 * step];
    amax_proc(d0, v,            magic, C, r0, c0, m0, m1, m2, m3);
    amax_proc(d1, v + step,     magic, C, r0, c0, m0, m1, m2, m3);
    amax_proc(d2, v + 2 * step, magic, C, r0, c0, m0, m1, m2, m3);
    amax_proc(d3, v + 3 * step, magic, C, r0, c0, m0, m1, m2, m3);
  }
  for (; v < nvec; v += step) {
    float4 d0 = A4[v];
    amax_proc(d0, v, magic, C, r0, c0, m0, m1, m2, m3);
  }
  #pragma unroll
  for (int off = 32; off > 0; off >>= 1) {
    m0 = fmaxf(m0, __shfl_xor(m0, off));
    m1 = fmaxf(m1, __shfl_xor(m1, off));
    m2 = fmaxf(m2, __shfl_xor(m2, off));
    m3 = fmaxf(m3, __shfl_xor(m3, off));
  }
  __shared__ float red[16];
  const int wave = tid >> 6;
  if ((tid & 63) == 0) {
    red[wave * 4 + 0] = m0;
    red[wave * 4 + 1] = m1;
    red[wave * 4 + 2] = m2;
    red[wave * 4 + 3] = m3;
  }
  __syncthreads();
  if (tid < 4) {
    float mm = fmaxf(fmaxf(red[tid], red[4 + tid]), fmaxf(red[8 + tid], red[12 + tid]));
    if (mm > 0.f) atomicMax((u32*)P + slotbase + tid, __float_as_uint(mm));
  }
}

// ---- fused absmax over all 4 tensors (one launch) ----
__global__ __launch_bounds__(256) void k_absmax4(const float* x, const float* Wu,
                                                 const float* Wg, const float* Wd,
                                                 u32 magic2048, u32 magic5504, float* P) {
  int b = blockIdx.x;
  if (b < 256)        absmax_dev((const float4*)x,  (1024 * 2048) >> 2, magic2048, 2048, 1024, 1024, SL_AX,    P, b,        256);
  else if (b < 768)   absmax_dev((const float4*)Wu, (5504 * 2048) >> 2, magic2048, 2048, 2752, 1024, SL_WUP,   P, b - 256,  512);
  else if (b < 1280)  absmax_dev((const float4*)Wg, (5504 * 2048) >> 2, magic2048, 2048, 2752, 1024, SL_WGATE, P, b - 768,  512);
  else                absmax_dev((const float4*)Wd, (2048 * 5504) >> 2, magic5504, 5504, 1024, 2752, SL_WDOWN, P, b - 1280, 512);
}

// ---- scales: s = max(absmax/qmax, 1e-8), qmax in {7,127} ----
__global__ void k_params1(float* P) {
  if (threadIdx.x != 0 || blockIdx.x != 0) return;
  u32* U = (u32*)P;
  float x00 = __uint_as_float(U[SL_AX + 0]);
  float x01 = __uint_as_float(U[SL_AX + 1]);
  float ax0 = x00;
  float ax1 = fmaxf(x00, x01);
  P[P_SX + 0] = fmaxf(ax0 / 7.f, 1e-8f);
  P[P_SX + 1] = fmaxf(ax0 / 127.f, 1e-8f);
  P[P_SX + 2] = fmaxf(ax1 / 7.f, 1e-8f);
  P[P_SX + 3] = fmaxf(ax1 / 127.f, 1e-8f);
  const int sl[3] = {SL_WUP, SL_WGATE, SL_WDOWN};
  const int sb[3] = {P_SWUP, P_SWGATE, P_SWDOWN};
  #pragma unroll
  for (int t = 0; t < 3; ++t) {
    float q00 = __uint_as_float(U[sl[t] + 0]);
    float q01 = __uint_as_float(U[sl[t] + 1]);
    float q10 = __uint_as_float(U[sl[t] + 2]);
    float q11 = __uint_as_float(U[sl[t] + 3]);
    float a0 = q00;
    float a1 = fmaxf(q00, q10);
    float a2 = fmaxf(q00, q01);
    float a3 = fmaxf(fmaxf(q00, q01), fmaxf(q10, q11));
    float aa[4] = {a0, a1, a2, a3};
    #pragma unroll
    for (int ij = 0; ij < 4; ++ij) {
      P[sb[t] + ij * 2 + 0] = fmaxf(aa[ij] / 7.f, 1e-8f);
      P[sb[t] + ij * 2 + 1] = fmaxf(aa[ij] / 127.f, 1e-8f);
    }
  }
}

__global__ void k_params2(float* P) {
  if (threadIdx.x != 0 || blockIdx.x != 0) return;
  u32* U = (u32*)P;
  float a0 = __uint_as_float(U[SL_AH]);
  float a1 = fmaxf(a0, __uint_as_float(U[SL_AH + 1]));
  P[P_SH + 0] = fmaxf(a0 / 7.f, 1e-8f);
  P[P_SH + 1] = fmaxf(a0 / 127.f, 1e-8f);
  P[P_SH + 2] = fmaxf(a1 / 7.f, 1e-8f);
  P[P_SH + 3] = fmaxf(a1 / 127.f, 1e-8f);
}

// ---- build combined activation operand, K-concat over in_sizes, hi/lo bf16,
//      stored chunk-XOR pre-swizzled: out chunk (kc>>3)&3 ^ ((row>>1)&3) ----
__global__ __launch_bounds__(256) void k_build_x(
    const float* __restrict__ src, const float* __restrict__ P,
    u16* __restrict__ Xh, u16* __restrict__ Xl,
    int rows, int Csrc, int cin0, int K, int sbx) {
  int kpr = K >> 3;
  int nch = rows * kpr;
  int gid = blockIdx.x * blockDim.x + threadIdx.x;
  if (gid >= nch) return;
  int row = gid / kpr;
  int kc_out = (gid - row * kpr) << 3;
  int kc_log = kc_out ^ (((row >> 1) & 3) << 3);
  int i = (kc_log >= cin0) ? 1 : 0;
  int c = kc_log - i * cin0;
  float pin = P[P_WH + i];
  float wa0 = P[P_WA], wa1 = P[P_WA + 1];
  float s4 = P[sbx + i * 2], s8 = P[sbx + i * 2 + 1];
  const float* sp = src + (size_t)row * Csrc + c;
  float v[8];
  *(float4*)&v[0] = *(const float4*)sp;
  *(float4*)&v[4] = *(const float4*)(sp + 4);
  short8 hv, lv;
  #pragma unroll
  for (int e = 0; e < 8; ++e) {
    float val = pin * (wa0 * fquant(v[e], s4) + wa1 * fquant(v[e], s8));
    u16 h = f2bf(val);
    hv[e] = (short)h;
    lv[e] = (short)f2bf(val - bf2f(h));
  }
  size_t off = (size_t)row * K + kc_out;
  *(short8*)(Xh + off) = hv;
  *(short8*)(Xl + off) = lv;
}

// ---- build combined weight operand (sum over out_sizes j and w_bits l) ----
__global__ __launch_bounds__(256) void k_build_w(
    const float* __restrict__ W, const float* __restrict__ P,
    u16* __restrict__ Wh, u16* __restrict__ Wl,
    int R, int Csrc, int cin0, int K, int sbw, int cout0) {
  int kpr = K >> 3;
  int nch = R * kpr;
  int gid = blockIdx.x * blockDim.x + threadIdx.x;
  if (gid >= nch) return;
  int row = gid / kpr;
  int kc_out = (gid - row * kpr) << 3;
  int kc_log = kc_out ^ (((row >> 1) & 3) << 3);
  int i = (kc_log >= cin0) ? 1 : 0;
  int c = kc_log - i * cin0;
  float wi0 = P[P_WI], wi1 = P[P_WI + 1];
  float ww0 = P[P_WW], ww1 = P[P_WW + 1];
  float s00 = P[sbw + i * 4 + 0];
  float s01 = P[sbw + i * 4 + 1];
  float s10 = P[sbw + i * 4 + 2];
  float s11 = P[sbw + i * 4 + 3];
  float keep0 = (row < cout0) ? wi0 : 0.f;
  const float* sp = W + (size_t)row * Csrc + c;
  float v[8];
  *(float4*)&v[0] = *(const float4*)sp;
  *(float4*)&v[4] = *(const float4*)(sp + 4);
  short8 hv, lv;
  #pragma unroll
  for (int e = 0; e < 8; ++e) {
    float w = v[e];
    float t0 = ww0 * fquant(w, s00) + ww1 * fquant(w, s01);
    float t1 = ww0 * fquant(w, s10) + ww1 * fquant(w, s11);
    float val = keep0 * t0 + wi1 * t1;
    u16 h = f2bf(val);
    hv[e] = (short)h;
    lv[e] = (short)f2bf(val - bf2f(h));
  }
  size_t off = (size_t)row * K + kc_out;
  *(short8*)(Wh + off) = hv;
  *(short8*)(Wl + off) = lv;
}

// ---- h = silu(gate)*up, fused h-absmax (cols<2752 / >=2752).
//      U_/G_ point at up/gate values, both with row stride `stride`. ----
__global__ __launch_bounds__(256) void k_h(const float* __restrict__ U_,
                                           const float* __restrict__ G_,
                                           int stride, float* __restrict__ H_,
                                           float* P) {
  int nvec = (1024 * 5504) >> 2;
  int gstride = gridDim.x * blockDim.x;
  float m0 = 0.f, m1 = 0.f;
  for (int v = blockIdx.x * blockDim.x + threadIdx.x; v < nvec; v += gstride) {
    int lin = v << 2;
    int r = lin / 5504;            // compile-time constant divisor -> magic mul
    int c = lin - r * 5504;
    size_t o = (size_t)r * stride + c;
    float4 u = *(const float4*)(U_ + o);
    float4 g = *(const float4*)(G_ + o);
    float4 h;
    h.x = u.x * (g.x / (1.f + expf(-g.x)));
    h.y = u.y * (g.y / (1.f + expf(-g.y)));
    h.z = u.z * (g.z / (1.f + expf(-g.z)));
    h.w = u.w * (g.w / (1.f + expf(-g.w)));
    ((float4*)H_)[v] = h;
    float mm = fmaxf(fmaxf(fabsf(h.x), fabsf(h.y)), fmaxf(fabsf(h.z), fabsf(h.w)));
    if (c < 2752) m0 = fmaxf(m0, mm); else m1 = fmaxf(m1, mm);
  }
  #pragma unroll
  for (int off = 32; off > 0; off >>= 1) {
    m0 = fmaxf(m0, __shfl_xor(m0, off));
    m1 = fmaxf(m1, __shfl_xor(m1, off));
  }
  if ((threadIdx.x & 63) == 0) {
    u32* slots = (u32*)P;
    if (m0 > 0.f) atomicMax(slots + SL_AH, __float_as_uint(m0));
    if (m1 > 0.f) atomicMax(slots + SL_AH + 1, __float_as_uint(m1));
  }
}

// ---- bf16x3 MFMA GEMM, depth-2 counted-vmcnt pipeline, XCD-swizzled,
//      optional split-K via gridDim.z. C[m,n] = sum_k A[m,k]*B[n,k].
//      WC = waves in N dir; waves = 2*WC; BM = MF*32, BN = NF*16*WC.
//      WC=4: 512 thr, 128x256 tile, 96KB LDS, 1 blk/CU, 2 waves/SIMD.
//      WC=2: 256 thr, 128x128 tile, 64KB LDS, 2 blk/CU (round-6 verified). ----
template <int MF, int NF, int WC>
__global__ __launch_bounds__(64 * 2 * WC) void k_gemm(
    const u16* __restrict__ Ah, const u16* __restrict__ Al,
    const u16* __restrict__ Bh, const u16* __restrict__ Bl,
    float* __restrict__ C, int M, int N, int K) {
  constexpr int WAVES = 2 * WC;
  constexpr int BM = MF * 32;
  constexpr int BN = NF * 16 * WC;
  constexpr int HALF = (2 * BM + 2 * BN) * 32;  // u16 elements per buffer
  constexpr int nsegA = BM / 16;
  constexpr int nsegB = BN / 16;
  constexpr int NSEG = 2 * nsegA + 2 * nsegB;
  constexpr int NJ = NSEG / WAVES;
  static_assert(NJ == 6 || NJ == 8, "vmcnt immediate must match NJ");
  __shared__ __align__(16) u16 S[2 * HALF];

  const int tid = threadIdx.x;
  const int wave = tid >> 6;
  const int lane = tid & 63;

  // XCD-bijective block swizzle (per z-slice)
  const int gx = gridDim.x;
  const int nwg = gx * gridDim.y;
  const int orig = blockIdx.y * gx + blockIdx.x;
  const int q = nwg >> 3, r = nwg & 7;
  const int xcd = orig & 7, linb = orig >> 3;
  const int swz = (xcd < r ? xcd * (q + 1) : r * (q + 1) + (xcd - r) * q) + linb;
  const int m0 = (swz % gx) * BM;
  const int n0 = (swz / gx) * BN;

  // split-K ranges from gridDim.z
  const int St = K >> 5;             // total K-steps of 32
  const int Z = gridDim.z;
  const int zb = St / Z, zr = St - zb * Z;
  const int z = blockIdx.z;
  const int nst = zb + ((z < zr) ? 1 : 0);
  const int k0 = (z * zb + ((z < zr) ? z : zr)) << 5;

  const int wr = wave / WC;          // 0..1
  const int wc = wave % WC;          // 0..WC-1
  const int lrow = lane >> 2;        // staging: row within 16-row segment
  const int lcol = (lane & 3) << 3;  // staging: col chunk
  const int fr = lane & 15;
  const int fq4 = (lane >> 4) << 2;
  const int kofs = (lane >> 4) << 3;

  f32x4 acc[MF][NF];
  #pragma unroll
  for (int m = 0; m < MF; ++m)
    #pragma unroll
    for (int n = 0; n < NF; ++n) acc[m][n] = (f32x4){0.f, 0.f, 0.f, 0.f};

  // staging sources (at k0) / LDS offsets
  const u16* srcp[NJ];
  int loff[NJ];
  #pragma unroll
  for (int j = 0; j < NJ; ++j) {
    int g = j * WAVES + wave;
    const u16* gb; int abase, trow, segi;
    if (g < nsegA)               { gb = Ah; abase = 0;                  trow = m0; segi = g; }
    else if (g < 2 * nsegA)      { gb = Al; abase = BM * 32;            trow = m0; segi = g - nsegA; }
    else if (g < 2 * nsegA + nsegB) { gb = Bh; abase = 2 * BM * 32;     trow = n0; segi = g - 2 * nsegA; }
    else                         { gb = Bl; abase = 2 * BM * 32 + BN * 32; trow = n0; segi = g - 2 * nsegA - nsegB; }
    srcp[j] = gb + (size_t)(trow + segi * 16 + lrow) * K + (k0 + lcol);
    loff[j] = abase + segi * 512;
  }

  // fragment LDS offsets (loop-invariant)
  int aoh[MF], aol[MF], boh[NF], bol[NF];
  #pragma unroll
  for (int m = 0; m < MF; ++m) {
    int rr = wr * (MF * 16) + m * 16 + fr;
    int idx = rr * 32 + (kofs ^ (((rr >> 1) & 3) << 3));
    aoh[m] = idx;
    aol[m] = BM * 32 + idx;
  }
  #pragma unroll
  for (int n = 0; n < NF; ++n) {
    int rr = wc * (NF * 16) + n * 16 + fr;
    int idx = rr * 32 + (kofs ^ (((rr >> 1) & 3) << 3));
    boh[n] = 2 * BM * 32 + idx;
    bol[n] = 2 * BM * 32 + BN * 32 + idx;
  }

  #define STAGE(bufo)                                           \
    { _Pragma("unroll")                                         \
      for (int j = 0; j < NJ; ++j) {                            \
        gload_lds16(srcp[j], S + (bufo) + loff[j]);             \
        srcp[j] += 32;                                          \
      } }

  #define COMPUTE(bufo)                                                         \
    { short8 afh[MF], afl[MF], bfh[NF], bfl[NF];                                \
      _Pragma("unroll")                                                         \
      for (int m = 0; m < MF; ++m) {                                            \
        afh[m] = *(const short8*)(S + (bufo) + aoh[m]);                         \
        afl[m] = *(const short8*)(S + (bufo) + aol[m]);                         \
      }                                                                         \
      _Pragma("unroll")                                                         \
      for (int n = 0; n < NF; ++n) {                                            \
        bfh[n] = *(const short8*)(S + (bufo) + boh[n]);                         \
        bfl[n] = *(const short8*)(S + (bufo) + bol[n]);                         \
      }                                                                         \
      _Pragma("unroll")                                                         \
      for (int m = 0; m < MF; ++m)                                              \
        _Pragma("unroll")                                                       \
        for (int n = 0; n < NF; ++n) {                                          \
          acc[m][n] = __builtin_amdgcn_mfma_f32_16x16x32_bf16(afh[m], bfh[n], acc[m][n], 0, 0, 0); \
          acc[m][n] = __builtin_amdgcn_mfma_f32_16x16x32_bf16(afh[m], bfl[n], acc[m][n], 0, 0, 0); \
          acc[m][n] = __builtin_amdgcn_mfma_f32_16x16x32_bf16(afl[m], bfh[n], acc[m][n], 0, 0, 0); \
        } }

  // depth-2 counted-vmcnt pipeline: stage(t+1) issued BEFORE compute(t);
  // its NJ loads stay in flight across both barriers (vmcnt(NJ), never 0 in-loop).
  int curo = 0;
  STAGE(curo);
  for (int t = 0; t + 1 < nst; ++t) {
    STAGE(curo ^ HALF);          // 2*NJ outstanding per wave
    if constexpr (NJ == 6) { WAITVM6(); } else { WAITVM8(); }
    BARRIER();                   // tile t landed for all waves
    COMPUTE(curo);
    BARRIER();                   // all waves done reading curo before next STAGE into it
    curo ^= HALF;
  }
  WAITVM0();                     // last tile's NJ
  BARRIER();
  COMPUTE(curo);

  #undef STAGE
  #undef COMPUTE

  float* Cz = C + (size_t)z * M * N;
  #pragma unroll
  for (int m = 0; m < MF; ++m) {
    #pragma unroll
    for (int n = 0; n < NF; ++n) {
      int row = m0 + wr * (MF * 16) + m * 16 + fq4;
      int col = n0 + wc * (NF * 16) + n * 16 + fr;
      float* cp = Cz + (size_t)row * N + col;
      f32x4 a = acc[m][n];
      cp[0] = a[0];
      cp[(size_t)N] = a[1];
      cp[(size_t)2 * N] = a[2];
      cp[(size_t)3 * N] = a[3];
    }
  }
}

// ---- out = p0 + p1 + p2 + p3 (split-K z=4 reduce, deterministic order) ----
__global__ __launch_bounds__(256) void k_reduce4(const float4* __restrict__ p,
                                                 float4* __restrict__ out, int nvec) {
  int stride = gridDim.x * blockDim.x;
  for (int i = blockIdx.x * blockDim.x + threadIdx.x; i < nvec; i += stride) {
    float4 a = p[i], b = p[nvec + i], c = p[2 * nvec + i], d = p[3 * nvec + i];
    float4 o;
    o.x = ((a.x + b.x) + c.x) + d.x;
    o.y = ((a.y + b.y) + c.y) + d.y;
    o.z = ((a.z + b.z) + c.z) + d.z;
    o.w = ((a.w + b.w) + c.w) + d.w;
    out[i] = o;
  }
}

extern "C" void kernel_launch(void* const* d_in, const int* in_sizes, int n_in,
                              void* d_out, int out_size, void* d_ws, size_t ws_size,
                              hipStream_t stream) {
  const float* x  = (const float*)d_in[0];
  const float* ph = (const float*)d_in[1];
  const float* pi = (const float*)d_in[2];
  const float* pa = (const float*)d_in[3];
  const float* pw = (const float*)d_in[4];
  const float* Wg = (const float*)d_in[5];
  const float* Wu = (const float*)d_in[6];
  const float* Wd = (const float*)d_in[7];
  float* out = (float*)d_out;

  const u32 magic2048 = (u32)(((1ULL << 40) + 2047ULL) / 2048ULL);
  const u32 magic5504 = (u32)(((1ULL << 40) + 5503ULL) / 5504ULL);
  char* ws = (char*)d_ws;

  // ---- fused layout (needs ~215.5 MB) ----
  const size_t szX1 = (size_t)1024 * 3072 * 2;          // 6.29 MB each
  const size_t szWug = (size_t)11008 * 3072 * 2;        // 67.63 MB each (h, l)
  const size_t szC = (size_t)1024 * 11008 * 4;          // 45.09 MB
  const size_t szH = (size_t)1024 * 5504 * 4;           // 22.54 MB
  const size_t fused_need = 1024 + 2 * szX1 + 2 * szWug + szC + szH;

  if (ws_size >= fused_need) {
    // ---------------- fused up+gate path (8-wave 128x256 GEMM) ----------------
    size_t off = 0;
    float* P = (float*)(ws + off); off += 1024;
    u16* X1h = (u16*)(ws + off); off += szX1;
    u16* X1l = (u16*)(ws + off); off += szX1;
    u16* Wh  = (u16*)(ws + off); off += szWug;   // rows 0..5503 Wu, 5504..11007 Wg
    u16* Wl  = (u16*)(ws + off); off += szWug;
    float* C = (float*)(ws + off); off += szC;   // [1024][11008] = [UP | GATE]
    float* H = (float*)(ws + off); off += szH;
    // reuse: X2 inside C (33.8 <= 45.1); down weights inside Wh/Wl heads;
    // DPART in Wh tail (disjoint from down-Wh head)
    u16* X2h = (u16*)C;
    u16* X2l = (u16*)C + (size_t)1024 * 8256;
    const size_t szWd = (size_t)2048 * 8256 * 2;   // 33.82 MB
    u16* Wdh = Wh;
    u16* Wdl = Wl;
    float* DPART = (float*)((char*)Wh + szWd);     // 33.55 MB fits in remaining 33.82

    k_init<<<1, 64, 0, stream>>>(ph, pi, pa, pw, P);
    k_absmax4<<<1792, 256, 0, stream>>>(x, Wu, Wg, Wd, magic2048, magic5504, P);
    k_params1<<<1, 64, 0, stream>>>(P);

    {
      int nch = 1024 * (3072 / 8);
      k_build_x<<<(nch + 255) / 256, 256, 0, stream>>>(x, P, X1h, X1l, 1024, 2048, 1024, 3072, P_SX);
    }
    {
      int nch = 5504 * (3072 / 8);
      k_build_w<<<(nch + 255) / 256, 256, 0, stream>>>(Wu, P, Wh, Wl, 5504, 2048, 1024, 3072, P_SWUP, 2752);
      k_build_w<<<(nch + 255) / 256, 256, 0, stream>>>(Wg, P, Wh + (size_t)5504 * 3072,
                                                       Wl + (size_t)5504 * 3072, 5504, 2048, 1024, 3072, P_SWGATE, 2752);
    }
    dim3 g1(1024 / 128, 11008 / 256, 1);   // 344 blocks, 512 threads, 1/CU
    k_gemm<4, 4, 4><<<g1, 512, 0, stream>>>(X1h, X1l, Wh, Wl, C, 1024, 11008, 3072);

    k_h<<<2048, 256, 0, stream>>>(C, C + 5504, 11008, H, P);
    k_params2<<<1, 64, 0, stream>>>(P);

    {
      int nch = 1024 * (8256 / 8);
      k_build_x<<<(nch + 255) / 256, 256, 0, stream>>>(H, P, X2h, X2l, 1024, 5504, 2752, 8256, P_SH);
    }
    {
      int nch = 2048 * (8256 / 8);
      k_build_w<<<(nch + 255) / 256, 256, 0, stream>>>(Wd, P, Wdh, Wdl, 2048, 5504, 2752, 8256, P_SWDOWN, 1024);
    }
    dim3 g2(1024 / 128, 2048 / 256, 4);    // 256 blocks = exactly 1/CU
    k_gemm<4, 4, 4><<<g2, 512, 0, stream>>>(X2h, X2l, Wdh, Wdl, DPART, 1024, 2048, 8256);
    k_reduce4<<<2048, 256, 0, stream>>>((const float4*)DPART, (float4*)out, (1024 * 2048) / 4);
    return;
  }

  // ---------------- fallback: round-6 layout (4-wave 128x128 GEMM) ----------------
  size_t off = 0;
  float* P = (float*)(ws + off); off += 1024;
  u16* X1h = (u16*)(ws + off); off += szX1;
  u16* X1l = (u16*)(ws + off); off += szX1;
  u16* Wh  = (u16*)(ws + off); off += (size_t)5504 * 3072 * 2;
  u16* Wl  = (u16*)(ws + off); off += (size_t)5504 * 3072 * 2;
  float* UP   = (float*)(ws + off); off += (size_t)1024 * 5504 * 4;
  float* GATE = (float*)(ws + off); off += (size_t)1024 * 5504 * 4;
  u16* X2h = (u16*)(ws + off); off += (size_t)1024 * 8256 * 2;
  u16* X2l = (u16*)(ws + off); off += (size_t)1024 * 8256 * 2;
  float* H = UP;
  float* DPART = UP;
  if (ws_size < off) return;

  k_init<<<1, 64, 0, stream>>>(ph, pi, pa, pw, P);
  k_absmax4<<<1792, 256, 0, stream>>>(x, Wu, Wg, Wd, magic2048, magic5504, P);
  k_params1<<<1, 64, 0, stream>>>(P);

  {
    int nch = 1024 * (3072 / 8);
    k_build_x<<<(nch + 255) / 256, 256, 0, stream>>>(x, P, X1h, X1l, 1024, 2048, 1024, 3072, P_SX);
  }
  {
    int nch = 5504 * (3072 / 8);
    k_build_w<<<(nch + 255) / 256, 256, 0, stream>>>(Wu, P, Wh, Wl, 5504, 2048, 1024, 3072, P_SWUP, 2752);
  }
  dim3 g1(1024 / 128, 5504 / 128, 1);
  k_gemm<4, 4, 2><<<g1, 256, 0, stream>>>(X1h, X1l, Wh, Wl, UP, 1024, 5504, 3072);
  {
    int nch = 5504 * (3072 / 8);
    k_build_w<<<(nch + 255) / 256, 256, 0, stream>>>(Wg, P, Wh, Wl, 5504, 2048, 1024, 3072, P_SWGATE, 2752);
  }
  k_gemm<4, 4, 2><<<g1, 256, 0, stream>>>(X1h, X1l, Wh, Wl, GATE, 1024, 5504, 3072);

  k_h<<<2048, 256, 0, stream>>>(UP, GATE, 5504, H, P);
  k_params2<<<1, 64, 0, stream>>>(P);

  {
    int nch = 1024 * (8256 / 8);
    k_build_x<<<(nch + 255) / 256, 256, 0, stream>>>(H, P, X2h, X2l, 1024, 5504, 2752, 8256, P_SH);
  }
  {
    int nch = 2048 * (8256 / 8);
    k_build_w<<<(nch + 255) / 256, 256, 0, stream>>>(Wd, P, Wh, Wl, 2048, 5504, 2752, 8256, P_SWDOWN, 1024);
  }
  dim3 g2(1024 / 128, 2048 / 128, 4);
  k_gemm<4, 4, 2><<<g2, 256, 0, stream>>>(X2h, X2l, Wh, Wl, DPART, 1024, 2048, 8256);
  k_reduce4<<<2048, 256, 0, stream>>>((const float4*)DPART, (float4*)out, (1024 * 2048) / 4);
}